// Round 1
// baseline (1450.964 us; speedup 1.0000x reference)
//
#include <hip/hip_runtime.h>
#include <math.h>

// Problem constants
#define BATCH 128
#define TENC  64
#define EE    256
#define DD    256
#define NSTEP 63

// Workspace layout (float offsets)
#define OFF_WA1T   0         // [512][256]  WA1T[k][j] = W_a1[j][k]          (h,c parts)
#define OFF_WHHT   131072    // [256][1024] WHHT[k][q] = W_hh[q][k]          (q = gate row)
#define OFF_WA1ET  393216    // [256][256]  WA1ET[k][j] = W_a1[j][512+k]     (enc part)
#define OFF_EPT    458752    // [128][256][64] EPT[b][j][t] = b_a1[j] + sum_k enc[b][t][k]*W_a1[j][512+k]
// total floats = 458752 + 2097152 = 2555904  (~9.75 MB)

__device__ __forceinline__ float ftanh(float x) {
    x = fminf(15.f, fmaxf(-15.f, x));
    float e = __expf(2.f * x);
    return (e - 1.f) / (e + 1.f);
}
__device__ __forceinline__ float fsig(float x) {
    return 1.f / (1.f + __expf(-x));
}

// ---------------------------------------------------------------------------
// Pre-kernel A: pack / transpose weights into ws
// ---------------------------------------------------------------------------
__global__ void pack_weights(const float* __restrict__ Wa1,
                             const float* __restrict__ Whh,
                             float* __restrict__ ws) {
    int idx = blockIdx.x * blockDim.x + threadIdx.x;
    if (idx < 131072) {
        // WA1T[k][j], k in [0,512): h cols then c cols
        int k = idx >> 8, j = idx & 255;
        ws[OFF_WA1T + idx] = Wa1[j * 768 + k];
    } else if (idx < 393216) {
        // WHHT: flat m = k*1024 + q  -> W_hh[q][k]
        int m = idx - 131072;
        int k = m >> 10, q = m & 1023;
        ws[OFF_WHHT + m] = Whh[q * 256 + k];
    } else if (idx < 458752) {
        // WA1ET[k][j] = W_a1[j][512+k]
        int n = idx - 393216;
        int k = n >> 8, j = n & 255;
        ws[OFF_WA1ET + n] = Wa1[j * 768 + 512 + k];
    }
}

// ---------------------------------------------------------------------------
// Pre-kernel B: EPT[b][j][t] = b_a1[j] + sum_k enc[b][t][k] * W_a1[j][512+k]
// grid: 256 blocks = (b, t-half), 256 threads
// ---------------------------------------------------------------------------
__global__ void enc_proj_kernel(const float* __restrict__ enc,
                                const float* __restrict__ ba1,
                                float* __restrict__ ws) {
    __shared__ float smem[8448];  // union: encs[32][256]=8192 then ept[256][33]=8448
    const int b  = blockIdx.x >> 1;
    const int th = blockIdx.x & 1;
    const int t0 = th * 32;
    const int tid = threadIdx.x;

    // stage enc tile [32][256]
    const float* encb = enc + (b * TENC + t0) * 256;
    for (int c = 0; c < 32; ++c) smem[c * 256 + tid] = encb[c * 256 + tid];
    __syncthreads();

    const int w = tid >> 6, l = tid & 63;   // wave = 8 t-rows, lane = 4 j's
    float acc[8][4];
    #pragma unroll
    for (int a = 0; a < 8; ++a)
        #pragma unroll
        for (int c = 0; c < 4; ++c) acc[a][c] = 0.f;

    const float4* WT = (const float4*)(ws + OFF_WA1ET);
    for (int k = 0; k < 256; ++k) {
        float4 wv = WT[k * 64 + l];
        #pragma unroll
        for (int tt = 0; tt < 8; ++tt) {
            float e = smem[(w * 8 + tt) * 256 + k];
            acc[tt][0] += e * wv.x; acc[tt][1] += e * wv.y;
            acc[tt][2] += e * wv.z; acc[tt][3] += e * wv.w;
        }
    }
    float4 bb = ((const float4*)ba1)[l];
    __syncthreads();
    // write transposed tile ept[256 j][33 (pad)]
    #pragma unroll
    for (int tt = 0; tt < 8; ++tt) {
        smem[(4 * l + 0) * 33 + w * 8 + tt] = acc[tt][0] + bb.x;
        smem[(4 * l + 1) * 33 + w * 8 + tt] = acc[tt][1] + bb.y;
        smem[(4 * l + 2) * 33 + w * 8 + tt] = acc[tt][2] + bb.z;
        smem[(4 * l + 3) * 33 + w * 8 + tt] = acc[tt][3] + bb.w;
    }
    __syncthreads();
    float* EPT = ws + OFF_EPT + b * 16384;
    for (int c = 0; c < 32; ++c) {
        int i = c * 256 + tid;
        int j = i >> 5, t5 = i & 31;
        EPT[j * 64 + t0 + t5] = smem[j * 33 + t5];
    }
}

// ---------------------------------------------------------------------------
// Main kernel: one workgroup per batch element, 512 threads, 63 scan steps
// ---------------------------------------------------------------------------
__global__ __launch_bounds__(512) void decoder_main(
    const float* __restrict__ enc, const float* __restrict__ yhist,
    const float* __restrict__ Wa2,
    const float* __restrict__ Wfc, const float* __restrict__ bfc,
    const float* __restrict__ wih, const float* __restrict__ bih,
    const float* __restrict__ bhh,
    const float* __restrict__ Wff, const float* __restrict__ bff,
    const float* __restrict__ ws, float* __restrict__ out) {

    __shared__ float hc[512];      // h = [0,256), c = [256,512)
    __shared__ float z[256];
    __shared__ float red[512];
    __shared__ float gbuf[1024];
    __shared__ float attnw[64];
    __shared__ float ctx[256];
    __shared__ float wa2s[256];
    __shared__ float wfcs[257];
    __shared__ float ytil_s;

    const int b    = blockIdx.x;
    const int tid  = threadIdx.x;
    const int lane = tid & 63;
    const int wv   = tid >> 6;

    hc[tid] = 0.f;                    // covers 512
    if (tid < 256) wa2s[tid] = Wa2[tid];
    if (tid < 257) wfcs[tid] = Wfc[tid];
    __syncthreads();

    const float*  WA1T = ws + OFF_WA1T;
    const float2* WHHT = (const float2*)(ws + OFF_WHHT);
    const float*  EPTb = ws + OFF_EPT + b * 16384;
    const float*  encb = enc + b * 16384;
    const float*  yb   = yhist + b * NSTEP;
    const float   bfc0 = bfc[0];

    for (int step = 0; step < NSTEP; ++step) {
        // ---- P1: z[j] = sum_k h[k]*Wh[j][k] + c[k]*Wc[j][k] ----
        {
            const int p = tid >> 8, j = tid & 255;   // p = k-half
            const float* Wp = WA1T + (p * 256) * 256 + j;
            float acc = 0.f;
            #pragma unroll 16
            for (int k = 0; k < 256; ++k)
                acc += Wp[k * 256] * hc[p * 256 + k];
            red[tid] = acc;
        }
        __syncthreads();
        if (tid < 256) z[tid] = red[tid] + red[256 + tid];
        __syncthreads();

        // ---- P2: scores s[t] = sum_j tanh(ep[t][j] + z[j]) * wa2[j]; softmax ----
        {
            float partial = 0.f;
            const float* ep = EPTb + lane;           // lane = t
            #pragma unroll 8
            for (int jj = 0; jj < 32; ++jj) {
                int j = wv * 32 + jj;
                float v = ep[j * 64] + z[j];
                partial += ftanh(v) * wa2s[j];
            }
            red[wv * 64 + lane] = partial;
        }
        __syncthreads();
        if (wv == 0) {
            float s = 0.f;
            #pragma unroll
            for (int w2 = 0; w2 < 8; ++w2) s += red[w2 * 64 + lane];
            float m = s;
            #pragma unroll
            for (int d = 32; d >= 1; d >>= 1) m = fmaxf(m, __shfl_xor(m, d));
            float e = __expf(s - m);
            float su = e;
            #pragma unroll
            for (int d = 32; d >= 1; d >>= 1) su += __shfl_xor(su, d);
            attnw[lane] = e / su;
        }
        __syncthreads();

        // ---- P3: ctx[e] = sum_t attn[t] * enc[t][e] ----
        {
            const int e = tid & 255, ph = tid >> 8;
            float partial = 0.f;
            const float* eb = encb + (ph * 32) * 256 + e;
            #pragma unroll 8
            for (int t2 = 0; t2 < 32; ++t2)
                partial += attnw[ph * 32 + t2] * eb[t2 * 256];
            red[tid] = partial;
        }
        __syncthreads();
        if (tid < 256) ctx[tid] = red[tid] + red[256 + tid];
        __syncthreads();
        if (tid < 64) {
            float partial = 0.f;
            #pragma unroll
            for (int q = 0; q < 4; ++q)
                partial += ctx[q * 64 + lane] * wfcs[q * 64 + lane];
            #pragma unroll
            for (int d = 32; d >= 1; d >>= 1) partial += __shfl_xor(partial, d);
            if (lane == 0) ytil_s = partial + wfcs[256] * yb[step] + bfc0;
        }
        __syncthreads();

        // ---- P4: gates[q] = ytil*wih[q] + b_ih[q] + b_hh[q] + sum_k h[k]*Whh[q][k] ----
        {
            float ytil = ytil_s;
            float ax = 0.f, ay = 0.f;
            const float2* Wp = WHHT + tid;           // q-pair = {2*tid, 2*tid+1}
            #pragma unroll 16
            for (int k = 0; k < 256; ++k) {
                float2 w2 = Wp[k * 512];
                float s = hc[k];
                ax += s * w2.x; ay += s * w2.y;
            }
            float2 wi = ((const float2*)wih)[tid];
            float2 bi = ((const float2*)bih)[tid];
            float2 bh = ((const float2*)bhh)[tid];
            gbuf[2 * tid]     = ax + ytil * wi.x + bi.x + bh.x;
            gbuf[2 * tid + 1] = ay + ytil * wi.y + bi.y + bh.y;
        }
        __syncthreads();
        // ---- update h, c (PyTorch gate order i,f,g,o) ----
        if (tid < 256) {
            float gi = gbuf[tid], gf = gbuf[256 + tid];
            float gg = gbuf[512 + tid], go = gbuf[768 + tid];
            float cn = fsig(gf) * hc[256 + tid] + fsig(gi) * ftanh(gg);
            float hn = fsig(go) * ftanh(cn);
            hc[tid] = hn; hc[256 + tid] = cn;
        }
        __syncthreads();
    }

    // ---- epilogue: out[b][r] = b_ff[r] + [h, ctx] . W_ff[r] ----
    if (wv < 2) {
        const float* wr = Wff + wv * 512;
        float partial = 0.f;
        #pragma unroll
        for (int q = 0; q < 8; ++q) {
            int e2 = q * 64 + lane;
            float v = (e2 < 256) ? hc[e2] : ctx[e2 - 256];
            partial += v * wr[e2];
        }
        #pragma unroll
        for (int d = 32; d >= 1; d >>= 1) partial += __shfl_xor(partial, d);
        if (lane == 0) out[b * 2 + wv] = partial + bff[wv];
    }
}

// ---------------------------------------------------------------------------
extern "C" void kernel_launch(void* const* d_in, const int* in_sizes, int n_in,
                              void* d_out, int out_size, void* d_ws, size_t ws_size,
                              hipStream_t stream) {
    const float* enc = (const float*)d_in[0];
    const float* yh  = (const float*)d_in[1];
    const float* Wa1 = (const float*)d_in[2];
    const float* ba1 = (const float*)d_in[3];
    const float* Wa2 = (const float*)d_in[4];
    // d_in[5] = b_a2 : softmax shift-invariant, unused
    const float* Wfc = (const float*)d_in[6];
    const float* bfc = (const float*)d_in[7];
    const float* Wih = (const float*)d_in[8];
    const float* Whh = (const float*)d_in[9];
    const float* bih = (const float*)d_in[10];
    const float* bhh = (const float*)d_in[11];
    const float* Wff = (const float*)d_in[12];
    const float* bff = (const float*)d_in[13];
    float* ws  = (float*)d_ws;
    float* out = (float*)d_out;

    hipLaunchKernelGGL(pack_weights, dim3(1792), dim3(256), 0, stream, Wa1, Whh, ws);
    hipLaunchKernelGGL(enc_proj_kernel, dim3(256), dim3(256), 0, stream, enc, ba1, ws);
    hipLaunchKernelGGL(decoder_main, dim3(BATCH), dim3(512), 0, stream,
                       enc, yh, Wa2, Wfc, bfc, Wih, bih, bhh, Wff, bff, ws, out);
}

// Round 2
// 1054.818 us; speedup vs baseline: 1.3756x; 1.3756x over previous
//
#include <hip/hip_runtime.h>
#include <math.h>

// Problem constants
#define BATCH 128
#define TENC  64
#define EE    256
#define DD    256
#define NSTEP 63

// Workspace layout (float offsets)
#define OFF_WA1T   0         // [512][256]  WA1T[k][j] = W_a1[j][k]          (h,c parts)
#define OFF_WHHT   131072    // [256][1024] WHHT[k][q] = W_hh[q][k]          (q = gate row)
#define OFF_WA1ET  393216    // [256][256]  WA1ET[k][j] = W_a1[j][512+k]     (enc part)
#define OFF_EPT    458752    // [128][256][64] EPT[b][j][t] = b_a1[j] + sum_k enc[b][t][k]*W_a1[j][512+k]

__device__ __forceinline__ float ftanh(float x) {
    x = fminf(15.f, fmaxf(-15.f, x));
    float e = __expf(2.f * x);
    return (e - 1.f) / (e + 1.f);
}
__device__ __forceinline__ float fsig(float x) {
    return 1.f / (1.f + __expf(-x));
}

// ---------------------------------------------------------------------------
// Pre-kernel A: pack / transpose weights into ws
// ---------------------------------------------------------------------------
__global__ void pack_weights(const float* __restrict__ Wa1,
                             const float* __restrict__ Whh,
                             float* __restrict__ ws) {
    int idx = blockIdx.x * blockDim.x + threadIdx.x;
    if (idx < 131072) {
        int k = idx >> 8, j = idx & 255;
        ws[OFF_WA1T + idx] = Wa1[j * 768 + k];
    } else if (idx < 393216) {
        int m = idx - 131072;
        int k = m >> 10, q = m & 1023;
        ws[OFF_WHHT + m] = Whh[q * 256 + k];
    } else if (idx < 458752) {
        int n = idx - 393216;
        int k = n >> 8, j = n & 255;
        ws[OFF_WA1ET + n] = Wa1[j * 768 + 512 + k];
    }
}

// ---------------------------------------------------------------------------
// Pre-kernel B: EPT[b][j][t] = b_a1[j] + sum_k enc[b][t][k] * W_a1[j][512+k]
// ---------------------------------------------------------------------------
__global__ void enc_proj_kernel(const float* __restrict__ enc,
                                const float* __restrict__ ba1,
                                float* __restrict__ ws) {
    __shared__ float smem[8448];
    const int b  = blockIdx.x >> 1;
    const int th = blockIdx.x & 1;
    const int t0 = th * 32;
    const int tid = threadIdx.x;

    const float* encb = enc + (b * TENC + t0) * 256;
    for (int c = 0; c < 32; ++c) smem[c * 256 + tid] = encb[c * 256 + tid];
    __syncthreads();

    const int w = tid >> 6, l = tid & 63;
    float acc[8][4];
    #pragma unroll
    for (int a = 0; a < 8; ++a)
        #pragma unroll
        for (int c = 0; c < 4; ++c) acc[a][c] = 0.f;

    const float4* WT = (const float4*)(ws + OFF_WA1ET);
    for (int k = 0; k < 256; ++k) {
        float4 wv = WT[k * 64 + l];
        #pragma unroll
        for (int tt = 0; tt < 8; ++tt) {
            float e = smem[(w * 8 + tt) * 256 + k];
            acc[tt][0] += e * wv.x; acc[tt][1] += e * wv.y;
            acc[tt][2] += e * wv.z; acc[tt][3] += e * wv.w;
        }
    }
    float4 bb = ((const float4*)ba1)[l];
    __syncthreads();
    #pragma unroll
    for (int tt = 0; tt < 8; ++tt) {
        smem[(4 * l + 0) * 33 + w * 8 + tt] = acc[tt][0] + bb.x;
        smem[(4 * l + 1) * 33 + w * 8 + tt] = acc[tt][1] + bb.y;
        smem[(4 * l + 2) * 33 + w * 8 + tt] = acc[tt][2] + bb.z;
        smem[(4 * l + 3) * 33 + w * 8 + tt] = acc[tt][3] + bb.w;
    }
    __syncthreads();
    float* EPT = ws + OFF_EPT + b * 16384;
    for (int c = 0; c < 32; ++c) {
        int i = c * 256 + tid;
        int j = i >> 5, t5 = i & 31;
        EPT[j * 64 + t0 + t5] = smem[j * 33 + t5];
    }
}

// ---------------------------------------------------------------------------
// Main kernel: one workgroup per batch element, 1024 threads, 63 scan steps.
// LDS-resident EPT + enc; per-step L2 traffic = weights only (1.5 MB).
// ---------------------------------------------------------------------------
__global__ __launch_bounds__(1024) void decoder_main(
    const float* __restrict__ enc, const float* __restrict__ yhist,
    const float* __restrict__ Wa2,
    const float* __restrict__ Wfc, const float* __restrict__ bfc,
    const float* __restrict__ wih, const float* __restrict__ bih,
    const float* __restrict__ bhh,
    const float* __restrict__ Wff, const float* __restrict__ bff,
    const float* __restrict__ ws, float* __restrict__ out) {

    __shared__ float hc[512];        // h = [0,256), c = [256,512)
    __shared__ float z[256];
    __shared__ float red1[1024];     // P1 partials [4 k-chunks][256 j]
    __shared__ float red2[1024];     // P2 partials [16 j-chunks][64 t]
    __shared__ float red3[1024];     // P3 partials [4 t-chunks][256 e]
    __shared__ float gbuf[1024];
    __shared__ float attnw[64];
    __shared__ float wa2s[256];
    __shared__ float wfcs[257];
    __shared__ float ys[64];
    __shared__ float ytil_s;
    __shared__ float epl[16384];     // EPT[b] : [256 j][64 t]
    __shared__ float encl[16384];    // enc[b] : [64 t][256 e]

    const int b    = blockIdx.x;
    const int tid  = threadIdx.x;
    const int lane = tid & 63;
    const int wv   = tid >> 6;

    // ---- stage per-batch data into LDS once ----
    const float* EPTb = ws + OFF_EPT + b * 16384;
    const float* encb = enc + b * 16384;
    #pragma unroll
    for (int i = 0; i < 16; ++i) {
        epl[i * 1024 + tid]  = EPTb[i * 1024 + tid];
        encl[i * 1024 + tid] = encb[i * 1024 + tid];
    }
    if (tid < 512) hc[tid] = 0.f;
    if (tid < 256) wa2s[tid] = Wa2[tid];
    if (tid < 257) wfcs[tid] = Wfc[tid];
    if (tid < NSTEP) ys[tid] = yhist[b * NSTEP + tid];
    const float bfc0 = bfc[0];
    const float wi   = wih[tid];                 // 4D x 1 -> per-thread gate row
    const float bsum = bih[tid] + bhh[tid];
    __syncthreads();

    const float* WA1T = ws + OFF_WA1T;
    const float* WHHT = ws + OFF_WHHT;

    for (int step = 0; step < NSTEP; ++step) {
        // ---- P1 partials: z[j] = sum_k hc[k] * WA1T[k][j]  (k split in 4) ----
        {
            const int p = tid >> 8, j = tid & 255;       // p = k-chunk of 128
            const float* Wp = WA1T + (p * 128) * 256 + j;
            const float* hp = hc + p * 128;
            float a0 = 0.f, a1 = 0.f;
            #pragma unroll 8
            for (int k = 0; k < 128; k += 2) {
                a0 += Wp[k * 256]       * hp[k];
                a1 += Wp[(k + 1) * 256] * hp[k + 1];
            }
            red1[p * 256 + j] = a0 + a1;
        }
        // ---- P4 accumulate (registers, no sync needed): gh[q] = h @ W_hh[q,:] ----
        float g0 = 0.f, g1 = 0.f;
        {
            const float* Wq = WHHT + tid;                // q = tid
            #pragma unroll 8
            for (int k = 0; k < 256; k += 2) {
                g0 += Wq[k * 1024]       * hc[k];
                g1 += Wq[(k + 1) * 1024] * hc[k + 1];
            }
        }
        __syncthreads();                                 // S1: red1 ready
        if (tid < 256)
            z[tid] = red1[tid] + red1[256 + tid] + red1[512 + tid] + red1[768 + tid];
        __syncthreads();                                 // S2: z ready

        // ---- P2: scores s[t] = sum_j tanh(ep[j][t] + z[j]) * wa2[j] ----
        {
            float partial = 0.f;
            const int jbase = wv * 16;
            #pragma unroll
            for (int jj = 0; jj < 16; ++jj) {
                const int j = jbase + jj;
                float v = epl[j * 64 + lane] + z[j];
                partial += ftanh(v) * wa2s[j];
            }
            red2[wv * 64 + lane] = partial;
        }
        __syncthreads();                                 // S3: red2 ready
        if (wv == 0) {
            float s = 0.f;
            #pragma unroll
            for (int w2 = 0; w2 < 16; ++w2) s += red2[w2 * 64 + lane];
            float m = s;
            #pragma unroll
            for (int d = 32; d >= 1; d >>= 1) m = fmaxf(m, __shfl_xor(m, d));
            float e = __expf(s - m);
            float su = e;
            #pragma unroll
            for (int d = 32; d >= 1; d >>= 1) su += __shfl_xor(su, d);
            attnw[lane] = e / su;
        }
        __syncthreads();                                 // S4: attnw ready

        // ---- P3: ctx partials ctx[e] = sum_t attn[t] * enc[t][e]  (t split in 4) ----
        {
            const int e = tid & 255, tc = tid >> 8;
            float partial = 0.f;
            #pragma unroll
            for (int i = 0; i < 16; ++i) {
                const int t = tc * 16 + i;
                partial += attnw[t] * encl[t * 256 + e];
            }
            red3[tc * 256 + e] = partial;
        }
        __syncthreads();                                 // S5: red3 ready
        if (wv == 0) {
            float partial = 0.f;
            #pragma unroll
            for (int q = 0; q < 4; ++q) {
                const int e2 = q * 64 + lane;
                float cv = red3[e2] + red3[256 + e2] + red3[512 + e2] + red3[768 + e2];
                partial += cv * wfcs[e2];
            }
            #pragma unroll
            for (int d = 32; d >= 1; d >>= 1) partial += __shfl_xor(partial, d);
            if (lane == 0) ytil_s = partial + wfcs[256] * ys[step] + bfc0;
        }
        __syncthreads();                                 // S6: ytil ready

        // ---- gates finalize + write ----
        gbuf[tid] = g0 + g1 + ytil_s * wi + bsum;
        __syncthreads();                                 // S7: gates ready

        // ---- h, c update (PyTorch gate order i,f,g,o) ----
        if (tid < 256) {
            float gi = gbuf[tid], gf = gbuf[256 + tid];
            float gg = gbuf[512 + tid], go = gbuf[768 + tid];
            float cn = fsig(gf) * hc[256 + tid] + fsig(gi) * ftanh(gg);
            float hn = fsig(go) * ftanh(cn);
            hc[tid] = hn; hc[256 + tid] = cn;
        }
        __syncthreads();                                 // S8: hc ready
    }

    // ---- epilogue: out[b][r] = b_ff[r] + [h, ctx] . W_ff[r]  (ctx from red3) ----
    if (wv < 2) {
        float partial = 0.f;
        #pragma unroll
        for (int qq = 0; qq < 8; ++qq) {
            const int e2 = qq * 64 + lane;
            float v;
            if (e2 < 256) {
                v = hc[e2];
            } else {
                const int e = e2 - 256;
                v = red3[e] + red3[256 + e] + red3[512 + e] + red3[768 + e];
            }
            partial += v * Wff[wv * 512 + e2];
        }
        #pragma unroll
        for (int d = 32; d >= 1; d >>= 1) partial += __shfl_xor(partial, d);
        if (lane == 0) out[b * 2 + wv] = partial + bff[wv];
    }
}

// ---------------------------------------------------------------------------
extern "C" void kernel_launch(void* const* d_in, const int* in_sizes, int n_in,
                              void* d_out, int out_size, void* d_ws, size_t ws_size,
                              hipStream_t stream) {
    const float* enc = (const float*)d_in[0];
    const float* yh  = (const float*)d_in[1];
    const float* Wa1 = (const float*)d_in[2];
    const float* ba1 = (const float*)d_in[3];
    const float* Wa2 = (const float*)d_in[4];
    // d_in[5] = b_a2 : softmax shift-invariant, unused
    const float* Wfc = (const float*)d_in[6];
    const float* bfc = (const float*)d_in[7];
    const float* Wih = (const float*)d_in[8];
    const float* Whh = (const float*)d_in[9];
    const float* bih = (const float*)d_in[10];
    const float* bhh = (const float*)d_in[11];
    const float* Wff = (const float*)d_in[12];
    const float* bff = (const float*)d_in[13];
    float* ws  = (float*)d_ws;
    float* out = (float*)d_out;

    hipLaunchKernelGGL(pack_weights, dim3(1792), dim3(256), 0, stream, Wa1, Whh, ws);
    hipLaunchKernelGGL(enc_proj_kernel, dim3(256), dim3(256), 0, stream, enc, ba1, ws);
    hipLaunchKernelGGL(decoder_main, dim3(BATCH), dim3(1024), 0, stream,
                       enc, yh, Wa2, Wfc, bfc, Wih, bih, bhh, Wff, bff, ws, out);
}